// Round 20
// baseline (146.131 us; speedup 1.0000x reference)
//
#include <hip/hip_runtime.h>
#include <hip/hip_bf16.h>

// SkipGCN: out = gcn(relu(gcn(x,W1,b1)),W2,b2) + x@Ws + bs
// N=100000, E=1600000, in=165, hid=128, out=2, fp32 in/out.
//
// R20 changes vs R19 (143.2us; gemm1 stuck at 47 across 3 staging rewrites;
// R14 counters show VGPR_Count=36 < bfr[12]'s 48 VGPRs -> compiler was
// REMATERIALIZING the B-fragment global loads inside the MFMA loop, making
// the K-loop memory-dependent; staging was never the bottleneck):
//  - gemm1: bfr loads moved AFTER the staging __syncthreads, immediately
//    before the MFMA loop. Short live range -> registers held; K-loop
//    becomes register-only. Verification signal: VGPR ~85-95.
//  - everything else identical to R19.

#define IND 165
#define HID 128
#define KP 192
#define BM 32
#define XSS2 208
#define SLAB 8192
#define EPB 4096
#define MAXNB 512

typedef __attribute__((ext_vector_type(8))) short short8v;
typedef __attribute__((ext_vector_type(4))) float float4v;
typedef __attribute__((ext_vector_type(2))) float float2v;

__device__ __forceinline__ unsigned short f2bf(float f) {
    unsigned u = __float_as_uint(f);
    unsigned r = (u + 0x7FFF + ((u >> 16) & 1)) >> 16;  // RNE
    return (unsigned short)r;
}
__device__ __forceinline__ float bf2f(unsigned short s) { return __uint_as_float(((unsigned)s) << 16); }

// ---- setup: w1t convert (blocks 0..95) + detect + zero bucket_len (block 96) ----
__global__ __launch_bounds__(256) void setup_kernel(const float* __restrict__ W1,
                                                    unsigned short* __restrict__ w1t,
                                                    const int* __restrict__ e32,
                                                    int* __restrict__ flag,
                                                    int* __restrict__ bucket_len, int NB) {
    int b = blockIdx.x;
    if (b < 96) {
        int t = b * 256 + threadIdx.x;
        int nn = t / KP, k = t - nn * KP;
        w1t[t] = (k < IND) ? f2bf(W1[k * HID + nn]) : (unsigned short)0;
    } else {
        __shared__ int nz;
        if (threadIdx.x == 0) nz = 0;
        __syncthreads();
        if (e32[2 * threadIdx.x + 1] != 0) atomicOr(&nz, 1);
        __syncthreads();
        if (threadIdx.x == 0) flag[0] = (nz == 0) ? 1 : 0;  // 1 => int64 layout
        for (int t = threadIdx.x; t < NB; t += 256) bucket_len[t] = 0;
    }
}

// ---- partition: edges -> per-bucket slabs of records (dstLow<<24 | src) ----
__global__ __launch_bounds__(256) void partition_kernel(const int* __restrict__ e32,
                                                        const int* __restrict__ flag,
                                                        int* __restrict__ bucket_len,
                                                        unsigned* __restrict__ slab,
                                                        int E, int NB) {
    __shared__ unsigned hist[MAXNB];
    __shared__ unsigned runbase[MAXNB];
    __shared__ unsigned cnt2[MAXNB];
    for (int t = threadIdx.x; t < NB; t += 256) { hist[t] = 0; cnt2[t] = 0; }
    __syncthreads();
    const int f = flag[0];
    const int base = blockIdx.x * EPB;
    unsigned rec[16];
    unsigned bk[16];
    if (f) {
        const int4* e4 = (const int4*)e32;
        #pragma unroll
        for (int j = 0; j < 8; ++j) {
            int p = (base >> 1) + j * 256 + threadIdx.x;
            int e = 2 * p;
            if (e < E) {
                int4 s4 = e4[p];
                int4 d4 = e4[(E >> 1) + p];
                rec[2 * j]     = ((unsigned)(d4.x & 255) << 24) | (unsigned)s4.x;
                bk[2 * j]      = (unsigned)d4.x >> 8;
                atomicAdd(&hist[bk[2 * j]], 1u);
                if (e + 1 < E) {
                    rec[2 * j + 1] = ((unsigned)(d4.z & 255) << 24) | (unsigned)s4.z;
                    bk[2 * j + 1]  = (unsigned)d4.z >> 8;
                    atomicAdd(&hist[bk[2 * j + 1]], 1u);
                } else {
                    bk[2 * j + 1] = 0xFFFFFFFFu; rec[2 * j + 1] = 0;
                }
            } else {
                bk[2 * j] = 0xFFFFFFFFu;     rec[2 * j] = 0;
                bk[2 * j + 1] = 0xFFFFFFFFu; rec[2 * j + 1] = 0;
            }
        }
    } else {
        #pragma unroll
        for (int j = 0; j < 16; ++j) {
            int e = base + j * 256 + threadIdx.x;
            if (e < E) {
                int src = e32[e];
                int dst = e32[E + e];
                unsigned b = (unsigned)dst >> 8;
                rec[j] = ((unsigned)(dst & 255) << 24) | (unsigned)src;
                bk[j] = b;
                atomicAdd(&hist[b], 1u);
            } else {
                bk[j] = 0xFFFFFFFFu;
                rec[j] = 0;
            }
        }
    }
    __syncthreads();
    for (int t = threadIdx.x; t < NB; t += 256) {
        unsigned h = hist[t];
        runbase[t] = h ? (unsigned)atomicAdd(&bucket_len[t], (int)h) : 0u;
    }
    __syncthreads();
    #pragma unroll
    for (int j = 0; j < 16; ++j) {
        unsigned b = bk[j];
        if (b != 0xFFFFFFFFu) {
            unsigned p = runbase[b] + atomicAdd(&cnt2[b], 1u);
            if (p < SLAB) slab[(size_t)b * SLAB + p] = rec[j];
        }
    }
}

// ---- buildB: block per bucket -> dinv, row2(beg,end padded x8), col_src (pads=n) ----
__global__ __launch_bounds__(256) void buildb_kernel(const unsigned* __restrict__ slab,
                                                     const int* __restrict__ bucket_len,
                                                     int2* __restrict__ row2,
                                                     float* __restrict__ dinv,
                                                     int* __restrict__ col_src, int n) {
    __shared__ unsigned deg[256];
    __shared__ int qa[256], qb[256];
    __shared__ unsigned cur[256];
    const int b = blockIdx.x;
    const int t = threadIdx.x;
    const int len = min(bucket_len[b], SLAB);
    const unsigned* recs = slab + (size_t)b * SLAB;
    const int d0 = b << 8;
    const int base = b * SLAB;
    deg[t] = 0;
    __syncthreads();
    for (int i = t; i < len; i += 256) atomicAdd(&deg[recs[i] >> 24], 1u);
    __syncthreads();
    const unsigned dv = deg[t];
    const int pdv = (int)((dv + 7u) & ~7u);
    qa[t] = pdv;
    __syncthreads();
    int* s = qa; int* d = qb;
    for (int off = 1; off < 256; off <<= 1) {
        d[t] = s[t] + ((t >= off) ? s[t - off] : 0);
        __syncthreads();
        int* tmp = s; s = d; d = tmp;
    }
    int pexcl = s[t] - pdv;
    int pend = min(pexcl + pdv, SLAB);
    if (pexcl > SLAB) pexcl = SLAB;
    if (d0 + t < n) {
        dinv[d0 + t] = rsqrtf(1.0f + (float)dv);
        row2[d0 + t] = make_int2(base + pexcl, base + pend);
    }
    cur[t] = (unsigned)pexcl;
    __syncthreads();
    for (int i = t; i < len; i += 256) {
        unsigned r = recs[i];
        unsigned p = atomicAdd(&cur[r >> 24], 1u);
        if (p < (unsigned)SLAB) col_src[base + p] = (int)(r & 0xFFFFFFu);
    }
    for (int p = pexcl + (int)dv; p < pend; ++p)
        col_src[base + p] = n;
}

// ---- MFMA gemm1: hb8 = (x@W1)*dinv, fused skip = x@Ws+bs+b2 ----
// bfr loaded AFTER staging barrier (short live range -> held in VGPRs).
__global__ __launch_bounds__(256, 4) void gemm1_kernel(const float* __restrict__ x,
                                                       const unsigned short* __restrict__ w1t,
                                                       const float* __restrict__ Ws,
                                                       const float* __restrict__ bs,
                                                       const float* __restrict__ b2,
                                                       const float* __restrict__ dinv,
                                                       unsigned char* __restrict__ hb8,
                                                       float* __restrict__ h2p,
                                                       float* __restrict__ skip, int n) {
    __shared__ unsigned short xs[BM * XSS2];
    __shared__ float sdinv[BM];
    __shared__ float2 wss[IND];
    const int row0 = blockIdx.x * BM;
    const int tid = threadIdx.x;
    const int wave = tid >> 6, lane = tid & 63;
    const int l15 = lane & 15, lk = (lane >> 4) * 8;

    if (blockIdx.x == 0) {
        if (tid < 32) ((unsigned*)(hb8 + (size_t)n * HID))[tid] = 0u;
        if (tid == 32) ((float2*)h2p)[n] = make_float2(0.f, 0.f);
    }
    if (tid < BM) sdinv[tid] = (row0 + tid < n) ? dinv[row0 + tid] : 1.f;
    if (tid < IND) wss[tid] = ((const float2*)Ws)[tid];

    for (int t = tid; t < BM * (XSS2 - IND); t += 256) {
        int r = t / (XSS2 - IND), k = IND + (t - r * (XSS2 - IND));
        xs[r * XSS2 + k] = 0;
    }
    {
        const int rows = min(BM, n - row0);
        if (rows == BM) {
            const float4* xs4 = (const float4*)(x + (size_t)row0 * IND);
            float4 v[6];
            #pragma unroll
            for (int j = 0; j < 5; ++j) v[j] = xs4[j * 256 + tid];
            if (tid < 40) v[5] = xs4[1280 + tid];
            #pragma unroll
            for (int j = 0; j < 6; ++j) {
                if (j == 5 && tid >= 40) break;
                int e0 = 4 * (j * 256 + tid);
                int r = e0 / IND, k = e0 - r * IND;
                xs[r * XSS2 + k] = f2bf(v[j].x);
                k++; if (k == IND) { k = 0; r++; }
                xs[r * XSS2 + k] = f2bf(v[j].y);
                k++; if (k == IND) { k = 0; r++; }
                xs[r * XSS2 + k] = f2bf(v[j].z);
                k++; if (k == IND) { k = 0; r++; }
                xs[r * XSS2 + k] = f2bf(v[j].w);
            }
        } else {
            const int nflt = rows * IND;
            const int nf2 = nflt >> 1;
            const float2* xsrc = (const float2*)(x + (size_t)row0 * IND);
            for (int f = tid; f < nf2; f += 256) {
                float2 v = xsrc[f];
                int e0 = 2 * f;
                int r0 = e0 / IND, k0 = e0 - r0 * IND;
                xs[r0 * XSS2 + k0] = f2bf(v.x);
                int r1 = (k0 == IND - 1) ? r0 + 1 : r0;
                int k1 = (k0 == IND - 1) ? 0 : k0 + 1;
                xs[r1 * XSS2 + k1] = f2bf(v.y);
            }
            if ((nflt & 1) && tid == 0) {
                int e = nflt - 1;
                int r = e / IND, k = e - r * IND;
                xs[r * XSS2 + k] = f2bf(x[(size_t)row0 * IND + e]);
            }
        }
    }
    __syncthreads();

    // B fragments: loaded HERE (post-barrier) so the live range is only the
    // MFMA loop -> held in VGPRs, loop is register-only.
    short8v bfr[12];
    #pragma unroll
    for (int nt2 = 0; nt2 < 2; ++nt2)
        #pragma unroll
        for (int ks = 0; ks < 6; ++ks)
            bfr[nt2 * 6 + ks] =
                *(const short8v*)(w1t + (size_t)((2 * wave + nt2) * 16 + l15) * KP + ks * 32 + lk);

    float4v acc[2][2];
    #pragma unroll
    for (int m = 0; m < 2; ++m)
        #pragma unroll
        for (int nt2 = 0; nt2 < 2; ++nt2) acc[m][nt2] = (float4v){0.f, 0.f, 0.f, 0.f};
    #pragma unroll
    for (int m = 0; m < 2; ++m) {
        const unsigned short* arow = xs + (m * 16 + l15) * XSS2;
        #pragma unroll
        for (int ks = 0; ks < 6; ++ks) {
            short8v a = *(const short8v*)(arow + ks * 32 + lk);
            acc[m][0] = __builtin_amdgcn_mfma_f32_16x16x32_bf16(a, bfr[ks], acc[m][0], 0, 0, 0);
            acc[m][1] = __builtin_amdgcn_mfma_f32_16x16x32_bf16(a, bfr[6 + ks], acc[m][1], 0, 0, 0);
        }
    }

    #pragma unroll
    for (int m = 0; m < 2; ++m) {
        int rib0 = m * 16 + (lane >> 4) * 4;
        #pragma unroll
        for (int nt2 = 0; nt2 < 2; ++nt2) {
            int col = (2 * wave + nt2) * 16 + l15;
            #pragma unroll
            for (int r = 0; r < 4; ++r) {
                int row = row0 + rib0 + r;
                float hv = acc[m][nt2][r] * sdinv[rib0 + r];
                int pk = __builtin_amdgcn_cvt_pk_fp8_f32(hv, 0.f, 0, false);
                if (row < n) hb8[(size_t)row * HID + col] = (unsigned char)(pk & 0xFF);
            }
        }
    }

    {
        int r = tid >> 3, j = tid & 7;
        int row = row0 + r;
        float s0 = 0.f, s1 = 0.f;
        if (row < n) {
            const unsigned short* xr = xs + r * XSS2;
            for (int k = j; k < IND; k += 8) {
                float xv = bf2f(xr[k]);
                float2 w = wss[k];
                s0 = fmaf(xv, w.x, s0);
                s1 = fmaf(xv, w.y, s1);
            }
        }
        s0 += __shfl_xor(s0, 1); s0 += __shfl_xor(s0, 2); s0 += __shfl_xor(s0, 4);
        s1 += __shfl_xor(s1, 1); s1 += __shfl_xor(s1, 2); s1 += __shfl_xor(s1, 4);
        if (j == 0 && row < n)
            ((float2*)skip)[row] = make_float2(s0 + bs[0] + b2[0], s1 + bs[1] + b2[1]);
    }
}

// ---- layer-1 aggregate (R12 structure) ----
__global__ __launch_bounds__(256) void agg1_kernel(const unsigned char* __restrict__ hb8,
                                                   const float* __restrict__ dinv,
                                                   const int2* __restrict__ row2,
                                                   const int* __restrict__ col_src,
                                                   const float* __restrict__ b1,
                                                   const float* __restrict__ W2,
                                                   float* __restrict__ h2p, int n) {
    int wid = threadIdx.x >> 6, lane = threadIdx.x & 63;
    int i = blockIdx.x * 4 + wid;
    if (i >= n) return;
    const int slot = lane >> 4, cl = lane & 15;
    const float di = dinv[i];
    float2v a0, a1, a2, a3;
    {
        uint2 r = *(const uint2*)(hb8 + (size_t)i * 128 + cl * 8);
        float w = (slot == 0) ? 1.f : 0.f;
        float2v wv = {w, w};
        a0 = __builtin_amdgcn_cvt_pk_f32_fp8((int)r.x, false) * wv;
        a1 = __builtin_amdgcn_cvt_pk_f32_fp8((int)r.x, true)  * wv;
        a2 = __builtin_amdgcn_cvt_pk_f32_fp8((int)r.y, false) * wv;
        a3 = __builtin_amdgcn_cvt_pk_f32_fp8((int)r.y, true)  * wv;
    }
    const int2 be = row2[i];
    const int beg  = __builtin_amdgcn_readfirstlane(be.x);
    const int endv = __builtin_amdgcn_readfirstlane(be.y);
    for (int e = beg; e < endv; e += 8) {
        int4 c0 = *(const int4*)(col_src + e);
        int4 c1 = *(const int4*)(col_src + e + 4);
        int sx0 = (slot & 1) ? c0.y : c0.x;
        int sy0 = (slot & 1) ? c0.w : c0.z;
        int s0  = (slot & 2) ? sy0 : sx0;
        int sx1 = (slot & 1) ? c1.y : c1.x;
        int sy1 = (slot & 1) ? c1.w : c1.z;
        int s1  = (slot & 2) ? sy1 : sx1;
        uint2 r0 = *(const uint2*)(hb8 + (size_t)s0 * 128 + cl * 8);
        uint2 r1 = *(const uint2*)(hb8 + (size_t)s1 * 128 + cl * 8);
        a0 += __builtin_amdgcn_cvt_pk_f32_fp8((int)r0.x, false);
        a1 += __builtin_amdgcn_cvt_pk_f32_fp8((int)r0.x, true);
        a2 += __builtin_amdgcn_cvt_pk_f32_fp8((int)r0.y, false);
        a3 += __builtin_amdgcn_cvt_pk_f32_fp8((int)r0.y, true);
        a0 += __builtin_amdgcn_cvt_pk_f32_fp8((int)r1.x, false);
        a1 += __builtin_amdgcn_cvt_pk_f32_fp8((int)r1.x, true);
        a2 += __builtin_amdgcn_cvt_pk_f32_fp8((int)r1.y, false);
        a3 += __builtin_amdgcn_cvt_pk_f32_fp8((int)r1.y, true);
    }
    float a[8] = {a0.x, a0.y, a1.x, a1.y, a2.x, a2.y, a3.x, a3.y};
    #pragma unroll
    for (int c = 0; c < 8; ++c) {
        a[c] += __shfl_xor(a[c], 16);
        a[c] += __shfl_xor(a[c], 32);
    }
    float4 bA = ((const float4*)b1)[2 * cl];
    float4 bB = ((const float4*)b1)[2 * cl + 1];
    float v0 = fmaxf(fmaf(di, a[0], bA.x), 0.f);
    float v1 = fmaxf(fmaf(di, a[1], bA.y), 0.f);
    float v2 = fmaxf(fmaf(di, a[2], bA.z), 0.f);
    float v3 = fmaxf(fmaf(di, a[3], bA.w), 0.f);
    float v4 = fmaxf(fmaf(di, a[4], bB.x), 0.f);
    float v5 = fmaxf(fmaf(di, a[5], bB.y), 0.f);
    float v6 = fmaxf(fmaf(di, a[6], bB.z), 0.f);
    float v7 = fmaxf(fmaf(di, a[7], bB.w), 0.f);
    float4 wA = ((const float4*)W2)[4 * cl];
    float4 wB = ((const float4*)W2)[4 * cl + 1];
    float4 wC = ((const float4*)W2)[4 * cl + 2];
    float4 wD = ((const float4*)W2)[4 * cl + 3];
    float p0 = v0 * wA.x + v1 * wA.z + v2 * wB.x + v3 * wB.z
             + v4 * wC.x + v5 * wC.z + v6 * wD.x + v7 * wD.z;
    float p1 = v0 * wA.y + v1 * wA.w + v2 * wB.y + v3 * wB.w
             + v4 * wC.y + v5 * wC.w + v6 * wD.y + v7 * wD.w;
    p0 += __shfl_xor(p0, 1); p0 += __shfl_xor(p0, 2);
    p0 += __shfl_xor(p0, 4); p0 += __shfl_xor(p0, 8);
    p1 += __shfl_xor(p1, 1); p1 += __shfl_xor(p1, 2);
    p1 += __shfl_xor(p1, 4); p1 += __shfl_xor(p1, 8);
    if (lane == 0) ((float2*)h2p)[i] = make_float2(p0 * di, p1 * di);
}

// ---- layer-2 aggregate + skip: 16 lanes per node, 4 nodes/wave ----
__global__ __launch_bounds__(256) void agg2_kernel(const float* __restrict__ h2p,
                                                   const float* __restrict__ dinv,
                                                   const int2* __restrict__ row2,
                                                   const int* __restrict__ col_src,
                                                   const float* __restrict__ skip,
                                                   float* __restrict__ out, int n) {
    const int tid = threadIdx.x;
    const int grp = tid >> 4;
    const int el  = tid & 15;
    const int i = blockIdx.x * 16 + grp;
    if (i >= n) return;
    const float di = dinv[i];
    const int2 be = row2[i];
    float a0 = 0.f, a1 = 0.f;
    for (int e = be.x + el; e < be.y; e += 16) {
        int s = col_src[e];
        float2 hs = ((const float2*)h2p)[s];
        a0 += hs.x;
        a1 += hs.y;
    }
    a0 += __shfl_xor(a0, 1); a0 += __shfl_xor(a0, 2);
    a0 += __shfl_xor(a0, 4); a0 += __shfl_xor(a0, 8);
    a1 += __shfl_xor(a1, 1); a1 += __shfl_xor(a1, 2);
    a1 += __shfl_xor(a1, 4); a1 += __shfl_xor(a1, 8);
    if (el == 0) {
        float2 self = ((const float2*)h2p)[i];
        float2 sk = ((const float2*)skip)[i];
        ((float2*)out)[i] = make_float2(di * (a0 + self.x) + sk.x,
                                        di * (a1 + self.y) + sk.y);
    }
}

extern "C" void kernel_launch(void* const* d_in, const int* in_sizes, int n_in,
                              void* d_out, int out_size, void* d_ws, size_t ws_size,
                              hipStream_t stream) {
    const float* x  = (const float*)d_in[0];
    const int*   ei = (const int*)d_in[1];
    const float* W1 = (const float*)d_in[2];
    const float* b1 = (const float*)d_in[3];
    const float* W2 = (const float*)d_in[4];
    const float* b2 = (const float*)d_in[5];
    const float* Ws = (const float*)d_in[6];
    const float* bs = (const float*)d_in[7];
    float* out = (float*)d_out;

    const int n = in_sizes[0] / IND;        // 100000
    const int E = in_sizes[1] / 2;          // 1600000
    const int NB = (n + 255) >> 8;          // 391 buckets

    char* ws = (char*)d_ws;
    size_t off = 0;
    auto alloc = [&](size_t bytes) { void* p = ws + off; off += (bytes + 255) & ~(size_t)255; return p; };
    int*            flag        = (int*)alloc(256);
    int*            bucket_len  = (int*)alloc((size_t)(MAXNB + 1) * 4);
    unsigned*       slab        = (unsigned*)alloc((size_t)NB * SLAB * 4);
    int2*           row2        = (int2*)alloc((size_t)n * 8);
    float*          dinv        = (float*)alloc((size_t)n * 4);
    int*            col_src     = (int*)alloc((size_t)NB * SLAB * 4);
    unsigned char*  hb8         = (unsigned char*)alloc((size_t)(n + 1) * HID);
    float*          h2p         = (float*)alloc((size_t)(n + 1) * 2 * 4);
    float*          skip        = (float*)alloc((size_t)n * 2 * 4);
    unsigned short* w1t         = (unsigned short*)alloc((size_t)HID * KP * 2);
    (void)ws_size;

    setup_kernel<<<97, 256, 0, stream>>>(W1, w1t, ei, flag, bucket_len, NB);
    partition_kernel<<<(E + EPB - 1) / EPB, 256, 0, stream>>>(ei, flag, bucket_len, slab, E, NB);
    buildb_kernel<<<NB, 256, 0, stream>>>(slab, bucket_len, row2, dinv, col_src, n);

    gemm1_kernel<<<(n + BM - 1) / BM, 256, 0, stream>>>(x, w1t, Ws, bs, b2, dinv, hb8, h2p, skip, n);
    agg1_kernel<<<(n + 3) / 4, 256, 0, stream>>>(hb8, dinv, row2, col_src, b1, W2, h2p, n);
    agg2_kernel<<<(n + 15) / 16, 256, 0, stream>>>(h2p, dinv, row2, col_src, skip, out, n);
}

// Round 21
// 143.140 us; speedup vs baseline: 1.0209x; 1.0209x over previous
//
#include <hip/hip_runtime.h>
#include <hip/hip_bf16.h>

// SkipGCN: out = gcn(relu(gcn(x,W1,b1)),W2,b2) + x@Ws + bs
// N=100000, E=1600000, in=165, hid=128, out=2, fp32 in/out.
//
// R21: revert R20's bfr placement to R19 (best-known 143.2us; R20's
// post-barrier bfr move was null-to-negative, remat theory refuted).
// Ledger at convergence:
//  - agg1 60us: 6 variants converged; warm==cold @ ~0 HBM -> LLC random-
//    gather latency floor. fp4 out of accuracy budget.
//  - gemm1 47us: 5 variants null -> composite floor (barrier + byte-store
//    epilogue + phase latencies).
//  - remaining ~36us across 13 small build/setup dispatches.

#define IND 165
#define HID 128
#define KP 192
#define BM 32
#define XSS2 208
#define SLAB 8192
#define EPB 4096
#define MAXNB 512

typedef __attribute__((ext_vector_type(8))) short short8v;
typedef __attribute__((ext_vector_type(4))) float float4v;
typedef __attribute__((ext_vector_type(2))) float float2v;

__device__ __forceinline__ unsigned short f2bf(float f) {
    unsigned u = __float_as_uint(f);
    unsigned r = (u + 0x7FFF + ((u >> 16) & 1)) >> 16;  // RNE
    return (unsigned short)r;
}
__device__ __forceinline__ float bf2f(unsigned short s) { return __uint_as_float(((unsigned)s) << 16); }

// ---- setup: w1t convert (blocks 0..95) + detect + zero bucket_len (block 96) ----
__global__ __launch_bounds__(256) void setup_kernel(const float* __restrict__ W1,
                                                    unsigned short* __restrict__ w1t,
                                                    const int* __restrict__ e32,
                                                    int* __restrict__ flag,
                                                    int* __restrict__ bucket_len, int NB) {
    int b = blockIdx.x;
    if (b < 96) {
        int t = b * 256 + threadIdx.x;
        int nn = t / KP, k = t - nn * KP;
        w1t[t] = (k < IND) ? f2bf(W1[k * HID + nn]) : (unsigned short)0;
    } else {
        __shared__ int nz;
        if (threadIdx.x == 0) nz = 0;
        __syncthreads();
        if (e32[2 * threadIdx.x + 1] != 0) atomicOr(&nz, 1);
        __syncthreads();
        if (threadIdx.x == 0) flag[0] = (nz == 0) ? 1 : 0;  // 1 => int64 layout
        for (int t = threadIdx.x; t < NB; t += 256) bucket_len[t] = 0;
    }
}

// ---- partition: edges -> per-bucket slabs of records (dstLow<<24 | src) ----
__global__ __launch_bounds__(256) void partition_kernel(const int* __restrict__ e32,
                                                        const int* __restrict__ flag,
                                                        int* __restrict__ bucket_len,
                                                        unsigned* __restrict__ slab,
                                                        int E, int NB) {
    __shared__ unsigned hist[MAXNB];
    __shared__ unsigned runbase[MAXNB];
    __shared__ unsigned cnt2[MAXNB];
    for (int t = threadIdx.x; t < NB; t += 256) { hist[t] = 0; cnt2[t] = 0; }
    __syncthreads();
    const int f = flag[0];
    const int base = blockIdx.x * EPB;
    unsigned rec[16];
    unsigned bk[16];
    if (f) {
        const int4* e4 = (const int4*)e32;
        #pragma unroll
        for (int j = 0; j < 8; ++j) {
            int p = (base >> 1) + j * 256 + threadIdx.x;
            int e = 2 * p;
            if (e < E) {
                int4 s4 = e4[p];
                int4 d4 = e4[(E >> 1) + p];
                rec[2 * j]     = ((unsigned)(d4.x & 255) << 24) | (unsigned)s4.x;
                bk[2 * j]      = (unsigned)d4.x >> 8;
                atomicAdd(&hist[bk[2 * j]], 1u);
                if (e + 1 < E) {
                    rec[2 * j + 1] = ((unsigned)(d4.z & 255) << 24) | (unsigned)s4.z;
                    bk[2 * j + 1]  = (unsigned)d4.z >> 8;
                    atomicAdd(&hist[bk[2 * j + 1]], 1u);
                } else {
                    bk[2 * j + 1] = 0xFFFFFFFFu; rec[2 * j + 1] = 0;
                }
            } else {
                bk[2 * j] = 0xFFFFFFFFu;     rec[2 * j] = 0;
                bk[2 * j + 1] = 0xFFFFFFFFu; rec[2 * j + 1] = 0;
            }
        }
    } else {
        #pragma unroll
        for (int j = 0; j < 16; ++j) {
            int e = base + j * 256 + threadIdx.x;
            if (e < E) {
                int src = e32[e];
                int dst = e32[E + e];
                unsigned b = (unsigned)dst >> 8;
                rec[j] = ((unsigned)(dst & 255) << 24) | (unsigned)src;
                bk[j] = b;
                atomicAdd(&hist[b], 1u);
            } else {
                bk[j] = 0xFFFFFFFFu;
                rec[j] = 0;
            }
        }
    }
    __syncthreads();
    for (int t = threadIdx.x; t < NB; t += 256) {
        unsigned h = hist[t];
        runbase[t] = h ? (unsigned)atomicAdd(&bucket_len[t], (int)h) : 0u;
    }
    __syncthreads();
    #pragma unroll
    for (int j = 0; j < 16; ++j) {
        unsigned b = bk[j];
        if (b != 0xFFFFFFFFu) {
            unsigned p = runbase[b] + atomicAdd(&cnt2[b], 1u);
            if (p < SLAB) slab[(size_t)b * SLAB + p] = rec[j];
        }
    }
}

// ---- buildB: block per bucket -> dinv, row2(beg,end padded x8), col_src (pads=n) ----
__global__ __launch_bounds__(256) void buildb_kernel(const unsigned* __restrict__ slab,
                                                     const int* __restrict__ bucket_len,
                                                     int2* __restrict__ row2,
                                                     float* __restrict__ dinv,
                                                     int* __restrict__ col_src, int n) {
    __shared__ unsigned deg[256];
    __shared__ int qa[256], qb[256];
    __shared__ unsigned cur[256];
    const int b = blockIdx.x;
    const int t = threadIdx.x;
    const int len = min(bucket_len[b], SLAB);
    const unsigned* recs = slab + (size_t)b * SLAB;
    const int d0 = b << 8;
    const int base = b * SLAB;
    deg[t] = 0;
    __syncthreads();
    for (int i = t; i < len; i += 256) atomicAdd(&deg[recs[i] >> 24], 1u);
    __syncthreads();
    const unsigned dv = deg[t];
    const int pdv = (int)((dv + 7u) & ~7u);
    qa[t] = pdv;
    __syncthreads();
    int* s = qa; int* d = qb;
    for (int off = 1; off < 256; off <<= 1) {
        d[t] = s[t] + ((t >= off) ? s[t - off] : 0);
        __syncthreads();
        int* tmp = s; s = d; d = tmp;
    }
    int pexcl = s[t] - pdv;
    int pend = min(pexcl + pdv, SLAB);
    if (pexcl > SLAB) pexcl = SLAB;
    if (d0 + t < n) {
        dinv[d0 + t] = rsqrtf(1.0f + (float)dv);
        row2[d0 + t] = make_int2(base + pexcl, base + pend);
    }
    cur[t] = (unsigned)pexcl;
    __syncthreads();
    for (int i = t; i < len; i += 256) {
        unsigned r = recs[i];
        unsigned p = atomicAdd(&cur[r >> 24], 1u);
        if (p < (unsigned)SLAB) col_src[base + p] = (int)(r & 0xFFFFFFu);
    }
    for (int p = pexcl + (int)dv; p < pend; ++p)
        col_src[base + p] = n;
}

// ---- MFMA gemm1: hb8 = (x@W1)*dinv, fused skip = x@Ws+bs+b2 ----
// float4 staging; bfr hoisted pre-staging (R19 placement, best-known).
__global__ __launch_bounds__(256, 4) void gemm1_kernel(const float* __restrict__ x,
                                                       const unsigned short* __restrict__ w1t,
                                                       const float* __restrict__ Ws,
                                                       const float* __restrict__ bs,
                                                       const float* __restrict__ b2,
                                                       const float* __restrict__ dinv,
                                                       unsigned char* __restrict__ hb8,
                                                       float* __restrict__ h2p,
                                                       float* __restrict__ skip, int n) {
    __shared__ unsigned short xs[BM * XSS2];
    __shared__ float sdinv[BM];
    __shared__ float2 wss[IND];
    const int row0 = blockIdx.x * BM;
    const int tid = threadIdx.x;
    const int wave = tid >> 6, lane = tid & 63;
    const int l15 = lane & 15, lk = (lane >> 4) * 8;

    if (blockIdx.x == 0) {
        if (tid < 32) ((unsigned*)(hb8 + (size_t)n * HID))[tid] = 0u;
        if (tid == 32) ((float2*)h2p)[n] = make_float2(0.f, 0.f);
    }
    if (tid < BM) sdinv[tid] = (row0 + tid < n) ? dinv[row0 + tid] : 1.f;
    if (tid < IND) wss[tid] = ((const float2*)Ws)[tid];

    short8v bfr[12];
    #pragma unroll
    for (int nt2 = 0; nt2 < 2; ++nt2)
        #pragma unroll
        for (int ks = 0; ks < 6; ++ks)
            bfr[nt2 * 6 + ks] =
                *(const short8v*)(w1t + (size_t)((2 * wave + nt2) * 16 + l15) * KP + ks * 32 + lk);

    for (int t = tid; t < BM * (XSS2 - IND); t += 256) {
        int r = t / (XSS2 - IND), k = IND + (t - r * (XSS2 - IND));
        xs[r * XSS2 + k] = 0;
    }
    {
        const int rows = min(BM, n - row0);
        if (rows == BM) {
            const float4* xs4 = (const float4*)(x + (size_t)row0 * IND);
            float4 v[6];
            #pragma unroll
            for (int j = 0; j < 5; ++j) v[j] = xs4[j * 256 + tid];
            if (tid < 40) v[5] = xs4[1280 + tid];
            #pragma unroll
            for (int j = 0; j < 6; ++j) {
                if (j == 5 && tid >= 40) break;
                int e0 = 4 * (j * 256 + tid);
                int r = e0 / IND, k = e0 - r * IND;
                xs[r * XSS2 + k] = f2bf(v[j].x);
                k++; if (k == IND) { k = 0; r++; }
                xs[r * XSS2 + k] = f2bf(v[j].y);
                k++; if (k == IND) { k = 0; r++; }
                xs[r * XSS2 + k] = f2bf(v[j].z);
                k++; if (k == IND) { k = 0; r++; }
                xs[r * XSS2 + k] = f2bf(v[j].w);
            }
        } else {
            const int nflt = rows * IND;
            const int nf2 = nflt >> 1;
            const float2* xsrc = (const float2*)(x + (size_t)row0 * IND);
            for (int f = tid; f < nf2; f += 256) {
                float2 v = xsrc[f];
                int e0 = 2 * f;
                int r0 = e0 / IND, k0 = e0 - r0 * IND;
                xs[r0 * XSS2 + k0] = f2bf(v.x);
                int r1 = (k0 == IND - 1) ? r0 + 1 : r0;
                int k1 = (k0 == IND - 1) ? 0 : k0 + 1;
                xs[r1 * XSS2 + k1] = f2bf(v.y);
            }
            if ((nflt & 1) && tid == 0) {
                int e = nflt - 1;
                int r = e / IND, k = e - r * IND;
                xs[r * XSS2 + k] = f2bf(x[(size_t)row0 * IND + e]);
            }
        }
    }
    __syncthreads();

    float4v acc[2][2];
    #pragma unroll
    for (int m = 0; m < 2; ++m)
        #pragma unroll
        for (int nt2 = 0; nt2 < 2; ++nt2) acc[m][nt2] = (float4v){0.f, 0.f, 0.f, 0.f};
    #pragma unroll
    for (int m = 0; m < 2; ++m) {
        const unsigned short* arow = xs + (m * 16 + l15) * XSS2;
        #pragma unroll
        for (int ks = 0; ks < 6; ++ks) {
            short8v a = *(const short8v*)(arow + ks * 32 + lk);
            acc[m][0] = __builtin_amdgcn_mfma_f32_16x16x32_bf16(a, bfr[ks], acc[m][0], 0, 0, 0);
            acc[m][1] = __builtin_amdgcn_mfma_f32_16x16x32_bf16(a, bfr[6 + ks], acc[m][1], 0, 0, 0);
        }
    }

    #pragma unroll
    for (int m = 0; m < 2; ++m) {
        int rib0 = m * 16 + (lane >> 4) * 4;
        #pragma unroll
        for (int nt2 = 0; nt2 < 2; ++nt2) {
            int col = (2 * wave + nt2) * 16 + l15;
            #pragma unroll
            for (int r = 0; r < 4; ++r) {
                int row = row0 + rib0 + r;
                float hv = acc[m][nt2][r] * sdinv[rib0 + r];
                int pk = __builtin_amdgcn_cvt_pk_fp8_f32(hv, 0.f, 0, false);
                if (row < n) hb8[(size_t)row * HID + col] = (unsigned char)(pk & 0xFF);
            }
        }
    }

    {
        int r = tid >> 3, j = tid & 7;
        int row = row0 + r;
        float s0 = 0.f, s1 = 0.f;
        if (row < n) {
            const unsigned short* xr = xs + r * XSS2;
            for (int k = j; k < IND; k += 8) {
                float xv = bf2f(xr[k]);
                float2 w = wss[k];
                s0 = fmaf(xv, w.x, s0);
                s1 = fmaf(xv, w.y, s1);
            }
        }
        s0 += __shfl_xor(s0, 1); s0 += __shfl_xor(s0, 2); s0 += __shfl_xor(s0, 4);
        s1 += __shfl_xor(s1, 1); s1 += __shfl_xor(s1, 2); s1 += __shfl_xor(s1, 4);
        if (j == 0 && row < n)
            ((float2*)skip)[row] = make_float2(s0 + bs[0] + b2[0], s1 + bs[1] + b2[1]);
    }
}

// ---- layer-1 aggregate (R12 structure) ----
__global__ __launch_bounds__(256) void agg1_kernel(const unsigned char* __restrict__ hb8,
                                                   const float* __restrict__ dinv,
                                                   const int2* __restrict__ row2,
                                                   const int* __restrict__ col_src,
                                                   const float* __restrict__ b1,
                                                   const float* __restrict__ W2,
                                                   float* __restrict__ h2p, int n) {
    int wid = threadIdx.x >> 6, lane = threadIdx.x & 63;
    int i = blockIdx.x * 4 + wid;
    if (i >= n) return;
    const int slot = lane >> 4, cl = lane & 15;
    const float di = dinv[i];
    float2v a0, a1, a2, a3;
    {
        uint2 r = *(const uint2*)(hb8 + (size_t)i * 128 + cl * 8);
        float w = (slot == 0) ? 1.f : 0.f;
        float2v wv = {w, w};
        a0 = __builtin_amdgcn_cvt_pk_f32_fp8((int)r.x, false) * wv;
        a1 = __builtin_amdgcn_cvt_pk_f32_fp8((int)r.x, true)  * wv;
        a2 = __builtin_amdgcn_cvt_pk_f32_fp8((int)r.y, false) * wv;
        a3 = __builtin_amdgcn_cvt_pk_f32_fp8((int)r.y, true)  * wv;
    }
    const int2 be = row2[i];
    const int beg  = __builtin_amdgcn_readfirstlane(be.x);
    const int endv = __builtin_amdgcn_readfirstlane(be.y);
    for (int e = beg; e < endv; e += 8) {
        int4 c0 = *(const int4*)(col_src + e);
        int4 c1 = *(const int4*)(col_src + e + 4);
        int sx0 = (slot & 1) ? c0.y : c0.x;
        int sy0 = (slot & 1) ? c0.w : c0.z;
        int s0  = (slot & 2) ? sy0 : sx0;
        int sx1 = (slot & 1) ? c1.y : c1.x;
        int sy1 = (slot & 1) ? c1.w : c1.z;
        int s1  = (slot & 2) ? sy1 : sx1;
        uint2 r0 = *(const uint2*)(hb8 + (size_t)s0 * 128 + cl * 8);
        uint2 r1 = *(const uint2*)(hb8 + (size_t)s1 * 128 + cl * 8);
        a0 += __builtin_amdgcn_cvt_pk_f32_fp8((int)r0.x, false);
        a1 += __builtin_amdgcn_cvt_pk_f32_fp8((int)r0.x, true);
        a2 += __builtin_amdgcn_cvt_pk_f32_fp8((int)r0.y, false);
        a3 += __builtin_amdgcn_cvt_pk_f32_fp8((int)r0.y, true);
        a0 += __builtin_amdgcn_cvt_pk_f32_fp8((int)r1.x, false);
        a1 += __builtin_amdgcn_cvt_pk_f32_fp8((int)r1.x, true);
        a2 += __builtin_amdgcn_cvt_pk_f32_fp8((int)r1.y, false);
        a3 += __builtin_amdgcn_cvt_pk_f32_fp8((int)r1.y, true);
    }
    float a[8] = {a0.x, a0.y, a1.x, a1.y, a2.x, a2.y, a3.x, a3.y};
    #pragma unroll
    for (int c = 0; c < 8; ++c) {
        a[c] += __shfl_xor(a[c], 16);
        a[c] += __shfl_xor(a[c], 32);
    }
    float4 bA = ((const float4*)b1)[2 * cl];
    float4 bB = ((const float4*)b1)[2 * cl + 1];
    float v0 = fmaxf(fmaf(di, a[0], bA.x), 0.f);
    float v1 = fmaxf(fmaf(di, a[1], bA.y), 0.f);
    float v2 = fmaxf(fmaf(di, a[2], bA.z), 0.f);
    float v3 = fmaxf(fmaf(di, a[3], bA.w), 0.f);
    float v4 = fmaxf(fmaf(di, a[4], bB.x), 0.f);
    float v5 = fmaxf(fmaf(di, a[5], bB.y), 0.f);
    float v6 = fmaxf(fmaf(di, a[6], bB.z), 0.f);
    float v7 = fmaxf(fmaf(di, a[7], bB.w), 0.f);
    float4 wA = ((const float4*)W2)[4 * cl];
    float4 wB = ((const float4*)W2)[4 * cl + 1];
    float4 wC = ((const float4*)W2)[4 * cl + 2];
    float4 wD = ((const float4*)W2)[4 * cl + 3];
    float p0 = v0 * wA.x + v1 * wA.z + v2 * wB.x + v3 * wB.z
             + v4 * wC.x + v5 * wC.z + v6 * wD.x + v7 * wD.z;
    float p1 = v0 * wA.y + v1 * wA.w + v2 * wB.y + v3 * wB.w
             + v4 * wC.y + v5 * wC.w + v6 * wD.y + v7 * wD.w;
    p0 += __shfl_xor(p0, 1); p0 += __shfl_xor(p0, 2);
    p0 += __shfl_xor(p0, 4); p0 += __shfl_xor(p0, 8);
    p1 += __shfl_xor(p1, 1); p1 += __shfl_xor(p1, 2);
    p1 += __shfl_xor(p1, 4); p1 += __shfl_xor(p1, 8);
    if (lane == 0) ((float2*)h2p)[i] = make_float2(p0 * di, p1 * di);
}

// ---- layer-2 aggregate + skip: 16 lanes per node, 4 nodes/wave ----
__global__ __launch_bounds__(256) void agg2_kernel(const float* __restrict__ h2p,
                                                   const float* __restrict__ dinv,
                                                   const int2* __restrict__ row2,
                                                   const int* __restrict__ col_src,
                                                   const float* __restrict__ skip,
                                                   float* __restrict__ out, int n) {
    const int tid = threadIdx.x;
    const int grp = tid >> 4;
    const int el  = tid & 15;
    const int i = blockIdx.x * 16 + grp;
    if (i >= n) return;
    const float di = dinv[i];
    const int2 be = row2[i];
    float a0 = 0.f, a1 = 0.f;
    for (int e = be.x + el; e < be.y; e += 16) {
        int s = col_src[e];
        float2 hs = ((const float2*)h2p)[s];
        a0 += hs.x;
        a1 += hs.y;
    }
    a0 += __shfl_xor(a0, 1); a0 += __shfl_xor(a0, 2);
    a0 += __shfl_xor(a0, 4); a0 += __shfl_xor(a0, 8);
    a1 += __shfl_xor(a1, 1); a1 += __shfl_xor(a1, 2);
    a1 += __shfl_xor(a1, 4); a1 += __shfl_xor(a1, 8);
    if (el == 0) {
        float2 self = ((const float2*)h2p)[i];
        float2 sk = ((const float2*)skip)[i];
        ((float2*)out)[i] = make_float2(di * (a0 + self.x) + sk.x,
                                        di * (a1 + self.y) + sk.y);
    }
}

extern "C" void kernel_launch(void* const* d_in, const int* in_sizes, int n_in,
                              void* d_out, int out_size, void* d_ws, size_t ws_size,
                              hipStream_t stream) {
    const float* x  = (const float*)d_in[0];
    const int*   ei = (const int*)d_in[1];
    const float* W1 = (const float*)d_in[2];
    const float* b1 = (const float*)d_in[3];
    const float* W2 = (const float*)d_in[4];
    const float* b2 = (const float*)d_in[5];
    const float* Ws = (const float*)d_in[6];
    const float* bs = (const float*)d_in[7];
    float* out = (float*)d_out;

    const int n = in_sizes[0] / IND;        // 100000
    const int E = in_sizes[1] / 2;          // 1600000
    const int NB = (n + 255) >> 8;          // 391 buckets

    char* ws = (char*)d_ws;
    size_t off = 0;
    auto alloc = [&](size_t bytes) { void* p = ws + off; off += (bytes + 255) & ~(size_t)255; return p; };
    int*            flag        = (int*)alloc(256);
    int*            bucket_len  = (int*)alloc((size_t)(MAXNB + 1) * 4);
    unsigned*       slab        = (unsigned*)alloc((size_t)NB * SLAB * 4);
    int2*           row2        = (int2*)alloc((size_t)n * 8);
    float*          dinv        = (float*)alloc((size_t)n * 4);
    int*            col_src     = (int*)alloc((size_t)NB * SLAB * 4);
    unsigned char*  hb8         = (unsigned char*)alloc((size_t)(n + 1) * HID);
    float*          h2p         = (float*)alloc((size_t)(n + 1) * 2 * 4);
    float*          skip        = (float*)alloc((size_t)n * 2 * 4);
    unsigned short* w1t         = (unsigned short*)alloc((size_t)HID * KP * 2);
    (void)ws_size;

    setup_kernel<<<97, 256, 0, stream>>>(W1, w1t, ei, flag, bucket_len, NB);
    partition_kernel<<<(E + EPB - 1) / EPB, 256, 0, stream>>>(ei, flag, bucket_len, slab, E, NB);
    buildb_kernel<<<NB, 256, 0, stream>>>(slab, bucket_len, row2, dinv, col_src, n);

    gemm1_kernel<<<(n + BM - 1) / BM, 256, 0, stream>>>(x, w1t, Ws, bs, b2, dinv, hb8, h2p, skip, n);
    agg1_kernel<<<(n + 3) / 4, 256, 0, stream>>>(hb8, dinv, row2, col_src, b1, W2, h2p, n);
    agg2_kernel<<<(n + 15) / 16, 256, 0, stream>>>(h2p, dinv, row2, col_src, skip, out, n);
}